// Round 5
// baseline (61.945 us; speedup 1.0000x reference)
//
#include <hip/hip_runtime.h>
#include <math.h>

// Canny NMS magnitude extractor: fused + separable + vectorized + LDS-overlaid
// + persistent 2-tile blocks with cross-tile register prefetch.
// x: [16,3,512,512] f32 -> out: [16,3,512,512] f32

#define HH 512
#define WW 512
#define CHX (HH * WW)
#define NB 16
#define TH 32            // output tile rows (y)
#define TW 64            // output tile cols (x)
#define GH 40
#define GW 72
#define GS 76
#define HS 68
#define BH 36
#define BS 68

__device__ __forceinline__ int reflect_i(int i, int n) {
    if (i < 0) i = -i;
    if (i >= n) i = 2 * n - 2 - i;
    return i;
}

// grayscale quad at (y, xs..xs+3) with reflect-x handling; y already reflected.
__device__ __forceinline__ float4 gray_quad(const float* __restrict__ inb, int y, int xs) {
    const float* p = inb + (size_t)y * WW;
    float4 gr;
    if (xs >= 0 && xs + 3 < WW) {
        float4 r  = *(const float4*)(p + xs);
        float4 g  = *(const float4*)(p + xs + CHX);
        float4 bl = *(const float4*)(p + xs + 2 * CHX);
        gr.x = r.x * 0.299f + g.x * 0.587f + bl.x * 0.114f;
        gr.y = r.y * 0.299f + g.y * 0.587f + bl.y * 0.114f;
        gr.z = r.z * 0.299f + g.z * 0.587f + bl.z * 0.114f;
        gr.w = r.w * 0.299f + g.w * 0.587f + bl.w * 0.114f;
    } else {
        float t[4];
        #pragma unroll
        for (int e = 0; e < 4; ++e) {
            int xm = reflect_i(xs + e, WW);
            t[e] = p[xm] * 0.299f + p[xm + CHX] * 0.587f + p[xm + 2 * CHX] * 0.114f;
        }
        gr.x = t[0]; gr.y = t[1]; gr.z = t[2]; gr.w = t[3];
    }
    return gr;
}

__device__ __forceinline__ void decode_tile(int T, int& tx0, int& ty0, int& b) {
    tx0 = (T & 7) * TW;          // 8 x-tiles
    ty0 = ((T >> 3) & 15) * TH;  // 16 y-tiles
    b   = T >> 7;                // image
}

__global__ __launch_bounds__(256, 4)
void canny_fused_kernel(const float* __restrict__ in, float* __restrict__ out) {
    const int tid = threadIdx.x;

    __shared__ float sPool[6338];             // 25352 B
    float*    sG = sPool;                     // 40*76 = 3040
    float*    sH = sPool + 3040;              // 40*68 = 2720
    float*    sB = sPool;                     // 36*68 = 2448, overlays gray
    float*    sM = sPool + 3040;              // 34*68 = 2312, overlays hblur
    unsigned* sF = (unsigned*)(sPool + 5760); // 34*17 = 578 words

    // Gaussian weights exactly as reference (f32 expf, f32-sum normalize)
    float g1[5];
    {
        float s = 0.f;
        #pragma unroll
        for (int i = 0; i < 5; ++i) {
            float a = (float)i - 2.0f;
            g1[i] = expf(-0.5f * a * a);
            s += g1[i];
        }
        #pragma unroll
        for (int i = 0; i < 5; ++i) g1[i] = g1[i] / s;
    }

    int tx0, ty0, b;
    decode_tile(blockIdx.x, tx0, ty0, b);
    const float* inb = in + (size_t)b * 3 * CHX;

    // ---- prefetch tile 0's gray into registers ----------------------------
    float4 pf[3];
    #pragma unroll
    for (int k = 0; k < 3; ++k) {
        int s = tid + k * 256;
        if (s < GH * (GW / 4)) {              // 720
            int j = s / 18, q = s - j * 18;
            int y = reflect_i(ty0 - 4 + j, HH);
            pf[k] = gray_quad(inb, y, tx0 - 4 + 4 * q);
        }
    }

    #pragma unroll 1
    for (int it = 0; it < 2; ++it) {
        if (it) __syncthreads();              // LDS reuse guard (prev P5 done)

        // ---- P1: write prefetched gray to LDS -----------------------------
        #pragma unroll
        for (int k = 0; k < 3; ++k) {
            int s = tid + k * 256;
            if (s < GH * (GW / 4)) {
                int j = s / 18, q = s - j * 18;
                *(float4*)(sG + j * GS + 4 * q) = pf[k];
            }
        }

        // ---- issue NEXT tile's prefetch (overlaps P2..P5 compute) ---------
        int ntx0 = tx0, nty0 = ty0, nb = b;
        const float* ninb = inb;
        if (it == 0) {
            decode_tile(blockIdx.x + 1024, ntx0, nty0, nb);
            ninb = in + (size_t)nb * 3 * CHX;
            #pragma unroll
            for (int k = 0; k < 3; ++k) {
                int s = tid + k * 256;
                if (s < GH * (GW / 4)) {
                    int j = s / 18, q = s - j * 18;
                    int y = reflect_i(nty0 - 4 + j, HH);
                    pf[k] = gray_quad(ninb, y, ntx0 - 4 + 4 * q);
                }
            }
        }
        __syncthreads();

        // ---- P2: horizontal gaussian, 4 outputs/thread --------------------
        #pragma unroll
        for (int k = 0; k < 3; ++k) {
            int s = tid + k * 256;
            if (s < GH * 17) {                // 680
                int j = s / 17, q = s - j * 17;
                int c0 = 4 * q;
                float4 a  = *(const float4*)(sG + j * GS + c0);
                float4 bq = *(const float4*)(sG + j * GS + c0 + 4);
                float v0 = a.x, v1 = a.y, v2 = a.z, v3 = a.w;
                float v4 = bq.x, v5 = bq.y, v6 = bq.z, v7 = bq.w;
                float4 o;
                o.x = g1[0]*v0 + g1[1]*v1 + g1[2]*v2 + g1[3]*v3 + g1[4]*v4;
                o.y = g1[0]*v1 + g1[1]*v2 + g1[2]*v3 + g1[3]*v4 + g1[4]*v5;
                o.z = g1[0]*v2 + g1[1]*v3 + g1[2]*v4 + g1[3]*v5 + g1[4]*v6;
                o.w = g1[0]*v3 + g1[1]*v4 + g1[2]*v5 + g1[3]*v6 + g1[4]*v7;
                *(float4*)(sH + j * HS + c0) = o;
            }
        }
        __syncthreads();

        // ---- edge fixup: sobel replicate pad in x -------------------------
        if (tx0 == 0) {
            if (tid < GH) {
                float v = sH[tid * HS + 2];
                sH[tid * HS + 0] = v;
                sH[tid * HS + 1] = v;
            }
            __syncthreads();
        }
        if (tx0 == WW - TW) {
            if (tid < GH) {
                float v = sH[tid * HS + 65];
                sH[tid * HS + 66] = v;
                sH[tid * HS + 67] = v;
            }
            __syncthreads();
        }

        // ---- P3: vertical gaussian (center-y clamped -> replicate pad y) --
        #pragma unroll
        for (int k = 0; k < 3; ++k) {
            int s = tid + k * 256;
            if (s < BH * 17) {                // 612
                int r = s / 17, q = s - r * 17;
                int c0 = 4 * q;
                int yc = min(max(ty0 - 2 + r, 0), HH - 1);
                int rb = yc - ty0 + 2;
                float4 o = make_float4(0.f, 0.f, 0.f, 0.f);
                #pragma unroll
                for (int t = 0; t < 5; ++t) {
                    float4 rw = *(const float4*)(sH + (rb + t) * HS + c0);
                    o.x += g1[t] * rw.x;
                    o.y += g1[t] * rw.y;
                    o.z += g1[t] * rw.z;
                    o.w += g1[t] * rw.w;
                }
                *(float4*)(sB + r * BS + c0) = o;
            }
        }
        __syncthreads();

        // ---- P4: sobel magnitude + packed direction flags -----------------
        #pragma unroll
        for (int k = 0; k < 3; ++k) {
            int s = tid + k * 256;
            if (s < 34 * 17) {                // 578
                int m = s / 17, q = s - m * 17;
                int c0 = 4 * q;
                int c4 = (q == 16) ? 64 : c0 + 4;
                float R[3][8];
                #pragma unroll
                for (int r = 0; r < 3; ++r) {
                    float4 a  = *(const float4*)(sB + (m + r) * BS + c0);
                    float4 bb = *(const float4*)(sB + (m + r) * BS + c4);
                    R[r][0] = a.x;  R[r][1] = a.y;  R[r][2] = a.z;  R[r][3] = a.w;
                    R[r][4] = bb.x; R[r][5] = bb.y; R[r][6] = bb.z; R[r][7] = bb.w;
                }
                int y = ty0 - 1 + m;
                bool yin = (y >= 0) && (y < HH);
                float mg[4]; unsigned pk = 0;
                #pragma unroll
                for (int li = 0; li < 4; ++li) {
                    float b00 = R[0][li], b01 = R[0][li+1], b02 = R[0][li+2];
                    float b10 = R[1][li],                   b12 = R[1][li+2];
                    float b20 = R[2][li], b21 = R[2][li+1], b22 = R[2][li+2];
                    float gx = ((((-b00 + b02) - 2.f * b10) + 2.f * b12) - b20) + b22;
                    float gy = ((((-b00 - 2.f * b01) - b02) + b20) + 2.f * b21) + b22;
                    int x = tx0 - 1 + c0 + li;
                    bool inimg = yin && (x >= 0) && (x < WW);
                    mg[li] = inimg ? sqrtf(gx * gx + gy * gy + 1e-6f) : 0.0f;
                    float adx = fabsf(gx), ady = fabsf(gy);
                    unsigned f = 0;
                    f |= (ady <= 0.41421356237309503f * adx) ? 1u : 0u;
                    f |= (ady >= 2.414213562373095f  * adx) ? 2u : 0u;
                    f |= (gy >= 0.f) ? 4u : 0u;
                    f |= (gx >= 0.f) ? 8u : 0u;
                    pk |= f << (8 * li);
                }
                float4 mv; mv.x = mg[0]; mv.y = mg[1]; mv.z = mg[2]; mv.w = mg[3];
                *(float4*)(sM + m * 68 + c0) = mv;
                sF[m * 17 + q] = pk;
            }
        }
        __syncthreads();

        // ---- P5: NMS select + clip + store x3 channels --------------------
        #pragma unroll
        for (int k = 0; k < 2; ++k) {
            int s = tid + k * 256;            // 512 exact
            int j = s >> 4, q = s & 15;
            int i0 = 4 * q;
            float W[3][6];
            #pragma unroll
            for (int r = 0; r < 3; ++r) {
                float4 a  = *(const float4*)(sM + (j + r) * 68 + i0);
                float2 bb = *(const float2*)(sM + (j + r) * 68 + i0 + 4);
                W[r][0] = a.x; W[r][1] = a.y; W[r][2] = a.z; W[r][3] = a.w;
                W[r][4] = bb.x; W[r][5] = bb.y;
            }
            unsigned w0 = sF[(j + 1) * 17 + q];
            unsigned w1 = sF[(j + 1) * 17 + q + 1];
            unsigned packed = (w0 >> 8) | (w1 << 24);

            float o[4];
            #pragma unroll
            for (int li = 0; li < 4; ++li) {
                float mc = W[1][li + 1];
                unsigned f = (packed >> (8 * li)) & 0xffu;
                bool h  = (f & 1u) != 0u;
                bool v  = (f & 2u) != 0u;
                bool sy = (f & 4u) != 0u;
                bool sx = (f & 8u) != 0u;
                float p0 = v ? W[0][li+1] : (sx ? W[0][li+2] : W[0][li]);
                float p1 = v ? W[1][li+1] : (sx ? W[1][li+2] : W[1][li]);
                float p2 = v ? W[2][li+1] : (sx ? W[2][li+2] : W[2][li]);
                float pv = h ? p1 : (sy ? p2 : p0);
                float n0 = v ? W[0][li+1] : (sx ? W[0][li] : W[0][li+2]);
                float n1 = v ? W[1][li+1] : (sx ? W[1][li] : W[1][li+2]);
                float n2 = v ? W[2][li+1] : (sx ? W[2][li] : W[2][li+2]);
                float nv = h ? n1 : (sy ? n0 : n2);
                o[li] = (mc > fmaxf(pv, nv)) ? fminf(mc, 1.0f) : 0.0f;
            }
            float4 ov; ov.x = o[0]; ov.y = o[1]; ov.z = o[2]; ov.w = o[3];
            int y = ty0 + j;
            float* op = out + ((size_t)(b * 3) * HH + y) * WW + tx0 + i0;
            *(float4*)op = ov;
            *(float4*)(op + (size_t)HH * WW) = ov;
            *(float4*)(op + (size_t)2 * HH * WW) = ov;
        }

        // advance to second tile
        tx0 = ntx0; ty0 = nty0; b = nb; inb = ninb;
    }
}

extern "C" void kernel_launch(void* const* d_in, const int* in_sizes, int n_in,
                              void* d_out, int out_size, void* d_ws, size_t ws_size,
                              hipStream_t stream) {
    const float* x = (const float*)d_in[0];
    float* out = (float*)d_out;
    dim3 grid(1024);   // 2048 tiles / 2 per block; all blocks resident (4/CU)
    dim3 block(256);
    hipLaunchKernelGGL(canny_fused_kernel, grid, block, 0, stream, x, out);
}

// Round 6
// 41.913 us; speedup vs baseline: 1.4779x; 1.4779x over previous
//
#include <hip/hip_runtime.h>
#include <math.h>

// Canny NMS magnitude extractor — barrier-free register-streaming version.
// One wave owns a 56-wide x 32-row output strip; the whole pipeline
// (gray -> hblur -> vblur -> sobel/mag/flags -> NMS) lives in rotating
// named registers. Horizontal stencils via ds_bpermute; vertical via the
// row-march. No LDS allocation, no __syncthreads.
// x: [16,3,512,512] f32 -> out: [16,3,512,512] f32

#define HH 512
#define WW 512
#define CHX (HH * WW)

__device__ __forceinline__ int reflect_i(int i, int n) {
    if (i < 0) i = -i;
    if (i >= n) i = 2 * n - 2 - i;
    return i;
}

__device__ __forceinline__ float bperm(int byteaddr, float v) {
    return __int_as_float(__builtin_amdgcn_ds_bpermute(byteaddr, __float_as_int(v)));
}

__global__ __launch_bounds__(64, 4)
void canny_stream_kernel(const float* __restrict__ in, float* __restrict__ out) {
    const int lane = threadIdx.x;          // 64-thread block == one wave
    const int Wid  = blockIdx.x;           // 0..2559
    const int sx = Wid % 10;               // 10 x-strips of 56 cols
    const int r1 = Wid / 10;
    const int sy = r1 & 15;                // 16 y-strips of 32 rows
    const int b  = r1 >> 4;                // image
    const int ty0 = sy * 32;
    const int x   = sx * 56 - 4 + lane;    // lane's column (outputs on lanes 4..59)

    // Gaussian weights exactly as reference (f32 expf, f32 left-to-right sum)
    float g1_0, g1_1, g1_2, g1_3, g1_4;
    {
        float e0 = expf(-2.0f), e1 = expf(-0.5f);
        float s = e0 + e1 + 1.0f + e1 + e0;      // left-to-right, same as ref
        g1_0 = e0 / s; g1_1 = e1 / s; g1_2 = 1.0f / s; g1_3 = e1 / s; g1_4 = e0 / s;
    }

    const float* ldb = in + (size_t)b * 3 * CHX + reflect_i(x, WW);  // column base
    const int xs_ = min(max(x, 0), WW - 1);
    float* ob = out + (size_t)b * 3 * CHX + xs_;                     // safe column base

    // bpermute byte addresses (wrap on out-of-range lanes is harmless: unconsumed)
    const int aL2 = 4 * (lane - 2), aL1 = 4 * (lane - 1);
    const int aR1 = 4 * (lane + 1), aR2 = 4 * (lane + 2);
    const int aSL = 4 * ((x == 0)      ? lane : lane - 1);  // sobel replicate-x left
    const int aSR = 4 * ((x == WW - 1) ? lane : lane + 1);  // sobel replicate-x right
    const bool do_store = (lane >= 4) && (lane <= 59) && (x < WW);

    // rotating pipeline state (all named scalars -> registers)
    float h0 = 0, h1 = 0, h2 = 0, h3 = 0, h4 = 0;                   // hblur rows t-4..t
    float bA = 0, bB = 0, bC = 0, bD = 0;                           // blur rows t-5..t-2
    float bLA = 0, bLB = 0, bLC = 0, bLD = 0;
    float bRA = 0, bRB = 0, bRC = 0, bRD = 0;
    float mA = 0, mB = 0, mC = 0, mD = 0;                           // mag rows t-7..t-4
    float mLA = 0, mLB = 0, mLC = 0, mLD = 0;
    float mRA = 0, mRB = 0, mRC = 0, mRD = 0;
    int   flB = 0, flC = 0, flD = 0;                                // flags t-6..t-4

    const int rlo = max(ty0 - 2, 0), rhi = min(ty0 + 33, HH - 1);   // blur rows computed
    const int mlo = ty0 - 1, mhi = ty0 + 32;                        // mag rows computed

    // prefetch first row (t = ty0-4)
    float cur_r, cur_g, cur_b2;
    {
        int yr = reflect_i(ty0 - 4, HH);
        const float* p = ldb + (size_t)yr * WW;
        cur_r = p[0]; cur_g = p[CHX]; cur_b2 = p[2 * CHX];
    }

    #pragma unroll 1
    for (int t = ty0 - 4; t <= ty0 + 37; ++t) {
        // ---- issue next row's loads (consumed next iteration) -------------
        float nr = 0.f, ng = 0.f, nb2 = 0.f;
        if (t + 1 <= ty0 + 35) {
            int yr = reflect_i(t + 1, HH);
            const float* p = ldb + (size_t)yr * WW;
            nr = p[0]; ng = p[CHX]; nb2 = p[2 * CHX];
        }

        // ---- rotate pipeline windows --------------------------------------
        bA = bB; bB = bC; bC = bD;
        bLA = bLB; bLB = bLC; bLC = bLD;
        bRA = bRB; bRB = bRC; bRC = bRD;
        mA = mB; mB = mC; mC = mD;
        mLA = mLB; mLB = mLC; mLC = mLD;
        mRA = mRB; mRB = mRC; mRC = mRD;
        flB = flC; flC = flD;
        h0 = h1; h1 = h2; h2 = h3; h3 = h4;

        // ---- NMS + store for row y = t-6 ----------------------------------
        int y = t - 6;
        if (y >= ty0 && y <= ty0 + 31) {
            float mc = mB;
            int f = flB;
            bool fh = (f & 1) != 0, fv = (f & 2) != 0;
            bool fsy = (f & 4) != 0, fsx = (f & 8) != 0;
            float p0 = fv ? mA : (fsx ? mRA : mLA);
            float p1 = fv ? mB : (fsx ? mRB : mLB);
            float p2 = fv ? mC : (fsx ? mRC : mLC);
            float pv = fh ? p1 : (fsy ? p2 : p0);
            float n0 = fv ? mA : (fsx ? mLA : mRA);
            float n1 = fv ? mB : (fsx ? mLB : mRB);
            float n2 = fv ? mC : (fsx ? mLC : mRC);
            float nv = fh ? n1 : (fsy ? n0 : n2);
            float o = (mc > fmaxf(pv, nv)) ? fminf(mc, 1.0f) : 0.0f;
            if (do_store) {
                float* q = ob + (size_t)y * WW;
                q[0] = o; q[CHX] = o; q[2 * CHX] = o;
            }
        }

        // ---- gray + hblur for row t (reflect handled at load) -------------
        float g = cur_r * 0.299f + cur_g * 0.587f + cur_b2 * 0.114f;
        float gl2 = bperm(aL2, g), gl1 = bperm(aL1, g);
        float gr1 = bperm(aR1, g), gr2 = bperm(aR2, g);
        h4 = g1_0 * gl2 + g1_1 * gl1 + g1_2 * g + g1_3 * gr1 + g1_4 * gr2;

        // ---- vblur row r = t-2 (reflect-pad exact: hb window is reflect rows)
        int r = t - 2;
        if (r >= rlo && r <= rhi) {
            bD = g1_0 * h0 + g1_1 * h1 + g1_2 * h2 + g1_3 * h3 + g1_4 * h4;
            bLD = bperm(aSL, bD);
            bRD = bperm(aSR, bD);
        }

        // ---- sobel magnitude + flags for row m = t-4 ----------------------
        int m = t - 4;
        if (m >= mlo && m <= mhi) {
            float A, AL, AR, C, CL, CR;
            if (m == 0)      { A = bB; AL = bLB; AR = bRB; }   // replicate-y top
            else             { A = bA; AL = bLA; AR = bRA; }
            if (m == HH - 1) { C = bB; CL = bLB; CR = bRB; }   // replicate-y bottom
            else             { C = bC; CL = bLC; CR = bRC; }
            float B_ = bB, BL = bLB, BR = bRB;
            (void)B_;
            float gx = ((((-AL + AR) - 2.f * BL) + 2.f * BR) - CL) + CR;
            float gy = ((((-AL - 2.f * A) - AR) + CL) + 2.f * C) + CR;
            bool inimg = (m >= 0) && (m < HH) && (x >= 0) && (x < WW);
            mD = inimg ? sqrtf(gx * gx + gy * gy + 1e-6f) : 0.0f;
            float adx = fabsf(gx), ady = fabsf(gy);
            int f = 0;
            f |= (ady <= 0.41421356237309503f * adx) ? 1 : 0;
            f |= (ady >= 2.414213562373095f  * adx) ? 2 : 0;
            f |= (gy >= 0.f) ? 4 : 0;
            f |= (gx >= 0.f) ? 8 : 0;
            flD = f;
            mLD = bperm(aL1, mD);
            mRD = bperm(aR1, mD);
        } else {
            mD = 0.f; mLD = 0.f; mRD = 0.f; flD = 0;
        }

        // ---- advance prefetch --------------------------------------------
        cur_r = nr; cur_g = ng; cur_b2 = nb2;
    }
}

extern "C" void kernel_launch(void* const* d_in, const int* in_sizes, int n_in,
                              void* d_out, int out_size, void* d_ws, size_t ws_size,
                              hipStream_t stream) {
    const float* x = (const float*)d_in[0];
    float* out = (float*)d_out;
    dim3 grid(2560);   // 10 x-strips * 16 y-strips * 16 images; 10 waves/CU exact
    dim3 block(64);    // one wave per block, no barriers
    hipLaunchKernelGGL(canny_stream_kernel, grid, block, 0, stream, x, out);
}

// Round 7
// 36.490 us; speedup vs baseline: 1.6976x; 1.1486x over previous
//
#include <hip/hip_runtime.h>
#include <math.h>

// Canny NMS magnitude extractor — barrier-free register-streaming version,
// 4 independent waves per block for occupancy.
// Each wave owns a 56-wide x 16-row output strip; the whole pipeline
// (gray -> hblur -> vblur -> sobel/mag/flags -> NMS) lives in rotating
// named registers. Horizontal stencils via ds_bpermute; vertical via the
// row-march. No LDS allocation, no __syncthreads.
// x: [16,3,512,512] f32 -> out: [16,3,512,512] f32

#define HH 512
#define WW 512
#define CHX (HH * WW)
#define TH 16            // strip height (output rows per wave)
#define NSX 10           // x-strips (56 cols each)
#define NSY (HH / TH)    // 32 y-strips

__device__ __forceinline__ int reflect_i(int i, int n) {
    if (i < 0) i = -i;
    if (i >= n) i = 2 * n - 2 - i;
    return i;
}

__device__ __forceinline__ float bperm(int byteaddr, float v) {
    return __int_as_float(__builtin_amdgcn_ds_bpermute(byteaddr, __float_as_int(v)));
}

__global__ __launch_bounds__(256, 8)
void canny_stream_kernel(const float* __restrict__ in, float* __restrict__ out) {
    const int lane = threadIdx.x & 63;
    const int sid  = blockIdx.x * 4 + (threadIdx.x >> 6);   // strip id, 0..5119
    const int sx = sid % NSX;
    const int r1 = sid / NSX;
    const int sy = r1 & (NSY - 1);
    const int b  = r1 >> 5;                 // log2(NSY)=5
    const int ty0 = sy * TH;
    const int x   = sx * 56 - 4 + lane;     // lane's column (outputs on lanes 4..59)

    // Gaussian weights exactly as reference (f32 expf, f32 left-to-right sum)
    float g1_0, g1_1, g1_2, g1_3, g1_4;
    {
        float e0 = expf(-2.0f), e1 = expf(-0.5f);
        float s = e0 + e1 + 1.0f + e1 + e0;
        g1_0 = e0 / s; g1_1 = e1 / s; g1_2 = 1.0f / s; g1_3 = e1 / s; g1_4 = e0 / s;
    }

    const float* ldb = in + (size_t)b * 3 * CHX + reflect_i(x, WW);  // column base
    const int xs_ = min(max(x, 0), WW - 1);
    float* ob = out + (size_t)b * 3 * CHX + xs_;                     // safe column base

    // bpermute byte addresses (per-wave local: lane index only)
    const int aL2 = 4 * (lane - 2), aL1 = 4 * (lane - 1);
    const int aR1 = 4 * (lane + 1), aR2 = 4 * (lane + 2);
    const int aSL = 4 * ((x == 0)      ? lane : lane - 1);  // sobel replicate-x left
    const int aSR = 4 * ((x == WW - 1) ? lane : lane + 1);  // sobel replicate-x right
    const bool do_store = (lane >= 4) && (lane <= 59) && (x < WW);

    // rotating pipeline state (all named scalars -> registers)
    float h0 = 0, h1 = 0, h2 = 0, h3 = 0, h4 = 0;                   // hblur rows t-4..t
    float bA = 0, bB = 0, bC = 0, bD = 0;                           // blur rows t-5..t-2
    float bLA = 0, bLB = 0, bLC = 0, bLD = 0;
    float bRA = 0, bRB = 0, bRC = 0, bRD = 0;
    float mA = 0, mB = 0, mC = 0, mD = 0;                           // mag rows t-7..t-4
    float mLA = 0, mLB = 0, mLC = 0, mLD = 0;
    float mRA = 0, mRB = 0, mRC = 0, mRD = 0;
    int   flB = 0, flC = 0, flD = 0;                                // flags t-6..t-4

    const int rlo = max(ty0 - 2, 0), rhi = min(ty0 + TH + 1, HH - 1); // blur rows
    const int mlo = ty0 - 1, mhi = ty0 + TH;                          // mag rows

    // prefetch first row (t = ty0-4)
    float cur_r, cur_g, cur_b2;
    {
        int yr = reflect_i(ty0 - 4, HH);
        const float* p = ldb + (size_t)yr * WW;
        cur_r = p[0]; cur_g = p[CHX]; cur_b2 = p[2 * CHX];
    }

    #pragma unroll 1
    for (int t = ty0 - 4; t <= ty0 + TH + 5; ++t) {
        // ---- issue next row's loads (consumed next iteration) -------------
        float nr = 0.f, ng = 0.f, nb2 = 0.f;
        if (t + 1 <= ty0 + TH + 3) {
            int yr = reflect_i(t + 1, HH);
            const float* p = ldb + (size_t)yr * WW;
            nr = p[0]; ng = p[CHX]; nb2 = p[2 * CHX];
        }

        // ---- rotate pipeline windows --------------------------------------
        bA = bB; bB = bC; bC = bD;
        bLA = bLB; bLB = bLC; bLC = bLD;
        bRA = bRB; bRB = bRC; bRC = bRD;
        mA = mB; mB = mC; mC = mD;
        mLA = mLB; mLB = mLC; mLC = mLD;
        mRA = mRB; mRB = mRC; mRC = mRD;
        flB = flC; flC = flD;
        h0 = h1; h1 = h2; h2 = h3; h3 = h4;

        // ---- NMS + store for row y = t-6 ----------------------------------
        int y = t - 6;
        if (y >= ty0 && y <= ty0 + TH - 1) {
            float mc = mB;
            int f = flB;
            bool fh = (f & 1) != 0, fv = (f & 2) != 0;
            bool fsy = (f & 4) != 0, fsx = (f & 8) != 0;
            float p0 = fv ? mA : (fsx ? mRA : mLA);
            float p1 = fv ? mB : (fsx ? mRB : mLB);
            float p2 = fv ? mC : (fsx ? mRC : mLC);
            float pv = fh ? p1 : (fsy ? p2 : p0);
            float n0 = fv ? mA : (fsx ? mLA : mRA);
            float n1 = fv ? mB : (fsx ? mLB : mRB);
            float n2 = fv ? mC : (fsx ? mLC : mRC);
            float nv = fh ? n1 : (fsy ? n0 : n2);
            float o = (mc > fmaxf(pv, nv)) ? fminf(mc, 1.0f) : 0.0f;
            if (do_store) {
                float* q = ob + (size_t)y * WW;
                q[0] = o; q[CHX] = o; q[2 * CHX] = o;
            }
        }

        // ---- gray + hblur for row t (reflect handled at load) -------------
        float g = cur_r * 0.299f + cur_g * 0.587f + cur_b2 * 0.114f;
        float gl2 = bperm(aL2, g), gl1 = bperm(aL1, g);
        float gr1 = bperm(aR1, g), gr2 = bperm(aR2, g);
        h4 = g1_0 * gl2 + g1_1 * gl1 + g1_2 * g + g1_3 * gr1 + g1_4 * gr2;

        // ---- vblur row r = t-2 (reflect-pad exact: hb window is reflect rows)
        int r = t - 2;
        if (r >= rlo && r <= rhi) {
            bD = g1_0 * h0 + g1_1 * h1 + g1_2 * h2 + g1_3 * h3 + g1_4 * h4;
            bLD = bperm(aSL, bD);
            bRD = bperm(aSR, bD);
        }

        // ---- sobel magnitude + flags for row m = t-4 ----------------------
        int m = t - 4;
        if (m >= mlo && m <= mhi) {
            float A, AL, AR, C, CL, CR;
            if (m == 0)      { A = bB; AL = bLB; AR = bRB; }   // replicate-y top
            else             { A = bA; AL = bLA; AR = bRA; }
            if (m == HH - 1) { C = bB; CL = bLB; CR = bRB; }   // replicate-y bottom
            else             { C = bC; CL = bLC; CR = bRC; }
            float BL = bLB, BR = bRB;
            float gx = ((((-AL + AR) - 2.f * BL) + 2.f * BR) - CL) + CR;
            float gy = ((((-AL - 2.f * A) - AR) + CL) + 2.f * C) + CR;
            bool inimg = (m >= 0) && (m < HH) && (x >= 0) && (x < WW);
            mD = inimg ? sqrtf(gx * gx + gy * gy + 1e-6f) : 0.0f;
            float adx = fabsf(gx), ady = fabsf(gy);
            int f = 0;
            f |= (ady <= 0.41421356237309503f * adx) ? 1 : 0;
            f |= (ady >= 2.414213562373095f  * adx) ? 2 : 0;
            f |= (gy >= 0.f) ? 4 : 0;
            f |= (gx >= 0.f) ? 8 : 0;
            flD = f;
            mLD = bperm(aL1, mD);
            mRD = bperm(aR1, mD);
        } else {
            mD = 0.f; mLD = 0.f; mRD = 0.f; flD = 0;
        }

        // ---- advance prefetch --------------------------------------------
        cur_r = nr; cur_g = ng; cur_b2 = nb2;
    }
}

extern "C" void kernel_launch(void* const* d_in, const int* in_sizes, int n_in,
                              void* d_out, int out_size, void* d_ws, size_t ws_size,
                              hipStream_t stream) {
    const float* x = (const float*)d_in[0];
    float* out = (float*)d_out;
    // 10 x-strips * 32 y-strips * 16 images = 5120 strips; 4 waves/block ->
    // 1280 blocks = exactly 5 blocks/CU, 20 waves/CU, zero tail.
    dim3 grid(1280);
    dim3 block(256);
    hipLaunchKernelGGL(canny_stream_kernel, grid, block, 0, stream, x, out);
}

// Round 8
// 34.658 us; speedup vs baseline: 1.7873x; 1.0529x over previous
//
#include <hip/hip_runtime.h>
#include <math.h>

// Canny NMS magnitude extractor — barrier-free register-streaming version.
// 4 independent waves per block; each wave owns a 56-wide x 16-row strip.
// Pipeline (gray -> hblur -> vblur -> sobel/mag/flags -> NMS) in rotating
// named registers; horizontal stencils via ds_bpermute. No LDS, no barriers.
// R8: #pragma unroll 2 (rotation-mov elimination) + 2-row-deep load prefetch.
// x: [16,3,512,512] f32 -> out: [16,3,512,512] f32

#define HH 512
#define WW 512
#define CHX (HH * WW)
#define TH 16            // strip height (output rows per wave)
#define NSX 10           // x-strips (56 cols each)
#define NSY (HH / TH)    // 32 y-strips

__device__ __forceinline__ int reflect_i(int i, int n) {
    if (i < 0) i = -i;
    if (i >= n) i = 2 * n - 2 - i;
    return i;
}

__device__ __forceinline__ float bperm(int byteaddr, float v) {
    return __int_as_float(__builtin_amdgcn_ds_bpermute(byteaddr, __float_as_int(v)));
}

__global__ __launch_bounds__(256, 8)
void canny_stream_kernel(const float* __restrict__ in, float* __restrict__ out) {
    const int lane = threadIdx.x & 63;
    const int sid  = blockIdx.x * 4 + (threadIdx.x >> 6);   // strip id, 0..5119
    const int sx = sid % NSX;
    const int r1 = sid / NSX;
    const int sy = r1 & (NSY - 1);
    const int b  = r1 >> 5;                 // log2(NSY)=5
    const int ty0 = sy * TH;
    const int x   = sx * 56 - 4 + lane;     // lane's column (outputs on lanes 4..59)

    // Gaussian weights exactly as reference (f32 expf, f32 left-to-right sum)
    float g1_0, g1_1, g1_2, g1_3, g1_4;
    {
        float e0 = expf(-2.0f), e1 = expf(-0.5f);
        float s = e0 + e1 + 1.0f + e1 + e0;
        g1_0 = e0 / s; g1_1 = e1 / s; g1_2 = 1.0f / s; g1_3 = e1 / s; g1_4 = e0 / s;
    }

    const float* ldb = in + (size_t)b * 3 * CHX + reflect_i(x, WW);  // column base
    const int xs_ = min(max(x, 0), WW - 1);
    float* ob = out + (size_t)b * 3 * CHX + xs_;                     // safe column base

    // bpermute byte addresses (per-wave local: lane index only)
    const int aL2 = 4 * (lane - 2), aL1 = 4 * (lane - 1);
    const int aR1 = 4 * (lane + 1), aR2 = 4 * (lane + 2);
    const int aSL = 4 * ((x == 0)      ? lane : lane - 1);  // sobel replicate-x left
    const int aSR = 4 * ((x == WW - 1) ? lane : lane + 1);  // sobel replicate-x right
    const bool do_store = (lane >= 4) && (lane <= 59) && (x < WW);
    const bool xin = (x >= 0) && (x < WW);                  // hoisted x-validity

    // rotating pipeline state (all named scalars -> registers)
    float h0 = 0, h1 = 0, h2 = 0, h3 = 0, h4 = 0;                   // hblur rows t-4..t
    float bA = 0, bB = 0, bC = 0, bD = 0;                           // blur rows t-5..t-2
    float bLA = 0, bLB = 0, bLC = 0, bLD = 0;
    float bRA = 0, bRB = 0, bRC = 0, bRD = 0;
    float mA = 0, mB = 0, mC = 0, mD = 0;                           // mag rows t-7..t-4
    float mLA = 0, mLB = 0, mLC = 0, mLD = 0;
    float mRA = 0, mRB = 0, mRC = 0, mRD = 0;
    int   flB = 0, flC = 0, flD = 0;                                // flags t-6..t-4

    const int rlo = max(ty0 - 2, 0), rhi = min(ty0 + TH + 1, HH - 1); // blur rows
    const int mlo = ty0 - 1, mhi = ty0 + TH;                          // mag rows

    // 2-deep row prefetch: c* = row t, n* = row t+1; issue t+2 inside loop.
    float c_r, c_g, c_b, n_r, n_g, n_b;
    {
        int y0r = reflect_i(ty0 - 4, HH);
        const float* p0 = ldb + (size_t)y0r * WW;
        c_r = p0[0]; c_g = p0[CHX]; c_b = p0[2 * CHX];
        int y1r = reflect_i(ty0 - 3, HH);
        const float* p1 = ldb + (size_t)y1r * WW;
        n_r = p1[0]; n_g = p1[CHX]; n_b = p1[2 * CHX];
    }

    #pragma unroll 2
    for (int t = ty0 - 4; t <= ty0 + TH + 5; ++t) {
        // ---- issue row t+2 loads (consumed 2 iterations later) ------------
        float f_r = 0.f, f_g = 0.f, f_b = 0.f;
        if (t + 2 <= ty0 + TH + 3) {
            int yr = reflect_i(t + 2, HH);
            const float* p = ldb + (size_t)yr * WW;
            f_r = p[0]; f_g = p[CHX]; f_b = p[2 * CHX];
        }

        // ---- rotate pipeline windows (renamed away by unroll) -------------
        bA = bB; bB = bC; bC = bD;
        bLA = bLB; bLB = bLC; bLC = bLD;
        bRA = bRB; bRB = bRC; bRC = bRD;
        mA = mB; mB = mC; mC = mD;
        mLA = mLB; mLB = mLC; mLC = mLD;
        mRA = mRB; mRB = mRC; mRC = mRD;
        flB = flC; flC = flD;
        h0 = h1; h1 = h2; h2 = h3; h3 = h4;

        // ---- NMS + store for row y = t-6 ----------------------------------
        int y = t - 6;
        if (y >= ty0 && y <= ty0 + TH - 1) {
            float mc = mB;
            int f = flB;
            bool fh = (f & 1) != 0, fv = (f & 2) != 0;
            bool fsy = (f & 4) != 0, fsx = (f & 8) != 0;
            float p0 = fv ? mA : (fsx ? mRA : mLA);
            float p1 = fv ? mB : (fsx ? mRB : mLB);
            float p2 = fv ? mC : (fsx ? mRC : mLC);
            float pv = fh ? p1 : (fsy ? p2 : p0);
            float n0 = fv ? mA : (fsx ? mLA : mRA);
            float n1 = fv ? mB : (fsx ? mLB : mRB);
            float n2 = fv ? mC : (fsx ? mLC : mRC);
            float nv = fh ? n1 : (fsy ? n0 : n2);
            float o = (mc > fmaxf(pv, nv)) ? fminf(mc, 1.0f) : 0.0f;
            if (do_store) {
                float* q = ob + (size_t)y * WW;
                q[0] = o; q[CHX] = o; q[2 * CHX] = o;
            }
        }

        // ---- gray + hblur for row t (reflect handled at load) -------------
        float g = c_r * 0.299f + c_g * 0.587f + c_b * 0.114f;
        float gl2 = bperm(aL2, g), gl1 = bperm(aL1, g);
        float gr1 = bperm(aR1, g), gr2 = bperm(aR2, g);
        h4 = g1_0 * gl2 + g1_1 * gl1 + g1_2 * g + g1_3 * gr1 + g1_4 * gr2;

        // ---- vblur row r = t-2 (reflect-pad exact: hb window is reflect rows)
        int r = t - 2;
        if (r >= rlo && r <= rhi) {
            bD = g1_0 * h0 + g1_1 * h1 + g1_2 * h2 + g1_3 * h3 + g1_4 * h4;
            bLD = bperm(aSL, bD);
            bRD = bperm(aSR, bD);
        }

        // ---- sobel magnitude + flags for row m = t-4 ----------------------
        int m = t - 4;
        if (m >= mlo && m <= mhi) {
            float A, AL, AR, C, CL, CR;
            if (m == 0)      { A = bB; AL = bLB; AR = bRB; }   // replicate-y top
            else             { A = bA; AL = bLA; AR = bRA; }
            if (m == HH - 1) { C = bB; CL = bLB; CR = bRB; }   // replicate-y bottom
            else             { C = bC; CL = bLC; CR = bRC; }
            float BL = bLB, BR = bRB;
            float gx = ((((-AL + AR) - 2.f * BL) + 2.f * BR) - CL) + CR;
            float gy = ((((-AL - 2.f * A) - AR) + CL) + 2.f * C) + CR;
            bool inimg = xin && (m >= 0) && (m < HH);
            mD = inimg ? sqrtf(gx * gx + gy * gy + 1e-6f) : 0.0f;
            float adx = fabsf(gx), ady = fabsf(gy);
            int f = 0;
            f |= (ady <= 0.41421356237309503f * adx) ? 1 : 0;
            f |= (ady >= 2.414213562373095f  * adx) ? 2 : 0;
            f |= (gy >= 0.f) ? 4 : 0;
            f |= (gx >= 0.f) ? 8 : 0;
            flD = f;
            mLD = bperm(aL1, mD);
            mRD = bperm(aR1, mD);
        } else {
            mD = 0.f; mLD = 0.f; mRD = 0.f; flD = 0;
        }

        // ---- advance prefetch pipeline ------------------------------------
        c_r = n_r; c_g = n_g; c_b = n_b;
        n_r = f_r; n_g = f_g; n_b = f_b;
    }
}

extern "C" void kernel_launch(void* const* d_in, const int* in_sizes, int n_in,
                              void* d_out, int out_size, void* d_ws, size_t ws_size,
                              hipStream_t stream) {
    const float* x = (const float*)d_in[0];
    float* out = (float*)d_out;
    // 10 x-strips * 32 y-strips * 16 images = 5120 strips; 4 waves/block ->
    // 1280 blocks = exactly 5 blocks/CU, 20 waves/CU, zero tail.
    dim3 grid(1280);
    dim3 block(256);
    hipLaunchKernelGGL(canny_stream_kernel, grid, block, 0, stream, x, out);
}